// Round 5
// baseline (703.345 us; speedup 1.0000x reference)
//
#include <hip/hip_runtime.h>
#include <hip/hip_bf16.h>

typedef __hip_bfloat16 bf16;
typedef unsigned short u16;

#define D 128
#define H 8
#define EDIM 16
#define SQRT_D 11.313708498984761f

typedef short bf16x8 __attribute__((ext_vector_type(8)));
typedef float f32x4 __attribute__((ext_vector_type(4)));

__device__ __forceinline__ float cvt(float v) { return v; }
__device__ __forceinline__ float cvt(bf16 v) { return __bfloat162float(v); }

// interleaved channel position: channel d -> (d&63)*2 + (d>>6)
__device__ __forceinline__ int ilv(int d) { return ((d & 63) << 1) | (d >> 6); }

__device__ __forceinline__ u16 f2bf_bits(float f) {
    union { bf16 h; u16 s; } cv; cv.h = __float2bfloat16(f); return cv.s;
}

// 16-lane all-reduce sum via DPP (pure VALU: xor1, xor2, half_mirror, mirror)
__device__ __forceinline__ float red16(float x) {
    x += __int_as_float(__builtin_amdgcn_update_dpp(0, __float_as_int(x), 0xB1, 0xf, 0xf, true));
    x += __int_as_float(__builtin_amdgcn_update_dpp(0, __float_as_int(x), 0x4E, 0xf, 0xf, true));
    x += __int_as_float(__builtin_amdgcn_update_dpp(0, __float_as_int(x), 0x141, 0xf, 0xf, true));
    x += __int_as_float(__builtin_amdgcn_update_dpp(0, __float_as_int(x), 0x140, 0xf, 0xf, true));
    return x;
}

// --------------------------------------- zero fill + dtype detect (block 0)
__global__ void k_zero_detect(int* p, int count,
                              const u16* __restrict__ u, int* flag)
{
    int i = blockIdx.x * blockDim.x + threadIdx.x;
    if (i < count) p[i] = 0;
    if (blockIdx.x == 0) {
        __shared__ int sh[256];
        int t = threadIdx.x;
        int cnt = 0;
        for (int k = t; k < 4096; k += 256) {
            int e = (u[k] >> 7) & 0xFF;
            cnt += (e > 132 && e < 255) ? 1 : 0;
        }
        sh[t] = cnt;
        __syncthreads();
        for (int s = 128; s > 0; s >>= 1) {
            if (t < s) sh[t] += sh[t + s];
            __syncthreads();
        }
        if (t == 0) *flag = (sh[0] > 100) ? 1 : 0;
    }
}

// ---------------------------------------------- CSR scan (single block)
__global__ __launch_bounds__(1024) void k_scan(
    const int* __restrict__ deg, int* __restrict__ row_ptr,
    int* __restrict__ cursor, int n)
{
    __shared__ int part[1024];
    const int t = threadIdx.x;
    const int chunk = (n + 1023) >> 10;
    const int beg = t * chunk;
    const int end = min(beg + chunk, n);
    int s = 0;
    for (int i = beg; i < end; ++i) s += deg[i];
    part[t] = s;
    __syncthreads();
    for (int off = 1; off < 1024; off <<= 1) {
        int v = (t >= off) ? part[t - off] : 0;
        __syncthreads();
        part[t] += v;
        __syncthreads();
    }
    int run = (t > 0) ? part[t - 1] : 0;
    for (int i = beg; i < end; ++i) {
        row_ptr[i] = run;
        cursor[i] = run;
        run += deg[i];
    }
    if (t == 1023) row_ptr[n] = part[1023];
}

// ------------------------------------------------------------ CSR scatter
__global__ void k_scatter(const int* __restrict__ ei, int* __restrict__ cursor,
                          int2* __restrict__ csr, int nE)
{
    int e = blockIdx.x * blockDim.x + threadIdx.x;
    if (e < nE) {
        int src = ei[e], dst = ei[nE + e];
        int pos = atomicAdd(&cursor[dst], 1);
        csr[pos] = make_int2(src, e);
    }
}

// --------------------------- node transform via MFMA (bf16 inputs) + hist
// GEMM: [64 rows of h] @ [Wl | Wr] (two 128x128 passes sharing the A tile).
// A tile LDS: At[64][136] bf16-bits (h = emb*sqrt(D)); B: Wt[d][k] padded.
// MFMA 16x16x32_bf16 layouts (guide-verified):
//   A[m=lane&15][k=quad*8+j], B[k=quad*8+j][n=lane&15],
//   C: col=lane&15, row=quad*4+reg.
#define MT 64
__global__ __launch_bounds__(256) void k_node_mfma(
    const int* __restrict__ x, const void* embv,
    const void* Wlv, const void* blv, const void* Wrv, const void* brv,
    float* __restrict__ xl, float* __restrict__ xr, int n, const int* flag,
    const int* __restrict__ ei, int* __restrict__ deg, int nE, int nodeBlocks)
{
    if ((int)blockIdx.x >= nodeBlocks) {              // fused dst-histogram
        int e = (blockIdx.x - nodeBlocks) * 256 + threadIdx.x;
        if (e < nE) atomicAdd(&deg[ei[nE + e]], 1);
        return;
    }
    if (*flag) return;                                // fp32 fallback kernel

    __shared__ u16 At[64 * 136];
    __shared__ u16 Bt[128 * 136];

    const u16* emb = (const u16*)embv;
    const int t = threadIdx.x;
    const int lane = t & 63;
    const int wv = t >> 6;
    const int R = blockIdx.x * MT;

    // ---- stage A: h rows R..R+63 as bf16, scaled by sqrt(D)
    {
        int row = t >> 2;
        int c0 = (t & 3) * 32;
        int node = R + row;
        uint4 u[4] = {};
        if (node < n) {
            int tok = x[node];
            const uint4* src = (const uint4*)(emb + (size_t)tok * D + c0);
            u[0] = src[0]; u[1] = src[1]; u[2] = src[2]; u[3] = src[3];
        }
        u16* dst = &At[row * 136 + c0];
        #pragma unroll
        for (int q = 0; q < 4; ++q) {
            unsigned w[4] = {u[q].x, u[q].y, u[q].z, u[q].w};
            uint4 o;
            unsigned* op = (unsigned*)&o;
            #pragma unroll
            for (int p = 0; p < 4; ++p) {
                float lo = __uint_as_float(w[p] << 16) * SQRT_D;
                float hi = __uint_as_float(w[p] & 0xffff0000u) * SQRT_D;
                op[p] = (unsigned)f2bf_bits(lo) | ((unsigned)f2bf_bits(hi) << 16);
            }
            *(uint4*)(dst + q * 8) = o;
        }
    }

    auto stageB = [&](const u16* W) {
        int k = t >> 1;
        int d0 = (t & 1) * 64;
        const uint4* src = (const uint4*)(W + k * D + d0);
        #pragma unroll
        for (int q = 0; q < 8; ++q) {
            uint4 u = src[q];
            unsigned w[4] = {u.x, u.y, u.z, u.w};
            #pragma unroll
            for (int p = 0; p < 4; ++p) {
                int d = d0 + q * 8 + p * 2;
                Bt[d * 136 + k]       = (u16)(w[p] & 0xffff);
                Bt[(d + 1) * 136 + k] = (u16)(w[p] >> 16);
            }
        }
    };

    const int m = lane & 15;
    const int quad = lane >> 4;

    auto mmPass = [&](const u16* biasp, float* out) {
        const u16* aBase = &At[(wv * 16 + m) * 136 + quad * 8];
        f32x4 acc[8];
        #pragma unroll
        for (int nt = 0; nt < 8; ++nt) {
            float bv = __uint_as_float(((unsigned)biasp[nt * 16 + m]) << 16);
            acc[nt] = f32x4{bv, bv, bv, bv};
        }
        #pragma unroll
        for (int kk = 0; kk < 128; kk += 32) {
            bf16x8 af = *(const bf16x8*)(aBase + kk);
            #pragma unroll
            for (int nt = 0; nt < 8; ++nt) {
                bf16x8 bfv = *(const bf16x8*)(&Bt[(nt * 16 + m) * 136 + quad * 8 + kk]);
                acc[nt] = __builtin_amdgcn_mfma_f32_16x16x32_bf16(af, bfv, acc[nt], 0, 0, 0);
            }
        }
        #pragma unroll
        for (int nt = 0; nt < 8; ++nt) {
            int id = ilv(nt * 16 + m);
            #pragma unroll
            for (int r = 0; r < 4; ++r) {
                int row = R + wv * 16 + quad * 4 + r;
                if (row < n) out[(size_t)row * D + id] = acc[nt][r];
            }
        }
    };

    stageB((const u16*)Wlv);
    __syncthreads();
    mmPass((const u16*)blv, xl);
    __syncthreads();
    stageB((const u16*)Wrv);
    __syncthreads();
    mmPass((const u16*)brv, xr);
}

// ---------------------- fp32 fallback node transform (early-exit if bf16)
__global__ __launch_bounds__(256) void k_node_f32(
    const int* __restrict__ x, const float* __restrict__ emb,
    const float* __restrict__ Wl, const float* __restrict__ bl,
    const float* __restrict__ Wr, const float* __restrict__ br,
    float* __restrict__ xl, float* __restrict__ xr, int n, const int* flag)
{
    if (*flag == 0) return;
    __shared__ float hS[8][D];
    const int t = threadIdx.x;
    const int d = t & (D - 1);
    const int r = t >> 7;
    const int id = ilv(d);

    for (int it = 0; it < 8; ++it) {
        int nb = blockIdx.x * MT + it * 8;
        #pragma unroll
        for (int j = 0; j < 4; ++j) {
            int row = r + 2 * j;
            int node = nb + row;
            float hv = 0.0f;
            if (node < n) hv = emb[(size_t)x[node] * D + d] * SQRT_D;
            hS[row][d] = hv;
        }
        __syncthreads();
        float accl[4], accr[4];
        const float blv = bl[d], brv = br[d];
        #pragma unroll
        for (int j = 0; j < 4; ++j) { accl[j] = blv; accr[j] = brv; }
        for (int k = 0; k < D; ++k) {
            float wl = Wl[k * D + d];
            float wr = Wr[k * D + d];
            #pragma unroll
            for (int j = 0; j < 4; ++j) {
                float hv = hS[r + 2 * j][k];
                accl[j] += hv * wl;
                accr[j] += hv * wr;
            }
        }
        #pragma unroll
        for (int j = 0; j < 4; ++j) {
            int node = nb + r + 2 * j;
            if (node < n) {
                xl[(size_t)node * D + id] = accl[j];
                xr[(size_t)node * D + id] = accr[j];
            }
        }
        __syncthreads();
    }
}

// ------------------------------------------------ per-edge W_e row registers
template <typename T> struct EwReg;
template <> struct EwReg<bf16> {
    unsigned v[8];
    __device__ __forceinline__ void load(const bf16* p, int e) {
        const uint4* q = (const uint4*)(p + (size_t)e * EDIM);
        uint4 A = q[0], B = q[1];
        v[0] = A.x; v[1] = A.y; v[2] = A.z; v[3] = A.w;
        v[4] = B.x; v[5] = B.y; v[6] = B.z; v[7] = B.w;
    }
    __device__ __forceinline__ float2 pair(int q) const {
        return make_float2(__uint_as_float(v[q] << 16),
                           __uint_as_float(v[q] & 0xffff0000u));
    }
};
template <> struct EwReg<float> {
    float v[16];
    __device__ __forceinline__ void load(const float* p, int e) {
        const float4* q = (const float4*)(p + (size_t)e * EDIM);
        float4 A = q[0], B = q[1], Cc = q[2], Dd = q[3];
        v[0]=A.x; v[1]=A.y; v[2]=A.z; v[3]=A.w;
        v[4]=B.x; v[5]=B.y; v[6]=B.z; v[7]=B.w;
        v[8]=Cc.x; v[9]=Cc.y; v[10]=Cc.z; v[11]=Cc.w;
        v[12]=Dd.x; v[13]=Dd.y; v[14]=Dd.z; v[15]=Dd.w;
    }
    __device__ __forceinline__ float2 pair(int q) const {
        return make_float2(v[2 * q], v[2 * q + 1]);
    }
};

// ------------------------------- node-centric aggregation, 1 wave = 1 node
// lane l owns channels d0=l, d1=l+64; DPP 16-lane reduction; 2-edge ILP.
template <typename T>
__device__ __forceinline__ void agg_body(
    const int* __restrict__ row_ptr, const int2* __restrict__ csr,
    const T* __restrict__ ew, const T* __restrict__ We,
    const T* __restrict__ att, const T* __restrict__ bias,
    const float* __restrict__ xl, const float* __restrict__ xr,
    float* __restrict__ vpre, float* __restrict__ bnsum,
    float* __restrict__ bnsumsq, int n)
{
    const int t = threadIdx.x;
    const int l = t & 63;
    const int slot = t >> 6;
    const int d0 = l, d1 = l + 64;

    float we0[EDIM], we1[EDIM];
    #pragma unroll
    for (int k = 0; k < EDIM; ++k) {
        we0[k] = cvt(We[k * D + d0]);
        we1[k] = cvt(We[k * D + d1]);
    }
    const float att0 = cvt(att[d0]), att1 = cvt(att[d1]);
    const float b0 = cvt(bias[d0]), b1 = cvt(bias[d1]);

    float s0 = 0, s20 = 0, s1 = 0, s21 = 0;
    const int nslots = gridDim.x * 4;

    for (int i = blockIdx.x * 4 + slot; i < n; i += nslots) {
        const int beg = row_ptr[i];
        const int end = row_ptr[i + 1];
        const int cnt = end - beg;
        const float2 xrv = *(const float2*)(xr + (size_t)i * D + 2 * l);
        float acc0 = 0, acc1 = 0, den0 = 0, den1 = 0;

        auto edge_eval = [&](const EwReg<T>& w, float2 xc) {
            float e0 = 0.f, e1 = 0.f;
            #pragma unroll
            for (int q = 0; q < 8; ++q) {
                float2 pr = w.pair(q);
                e0 = fmaf(pr.y, we0[2 * q + 1], fmaf(pr.x, we0[2 * q], e0));
                e1 = fmaf(pr.y, we1[2 * q + 1], fmaf(pr.x, we1[2 * q], e1));
            }
            float z0 = xc.x + xrv.x + e0;
            float z1 = xc.y + xrv.y + e1;
            float m0 = z0 > 0.f ? z0 : 0.2f * z0;   // leaky_relu 0.2
            float m1 = z1 > 0.f ? z1 : 0.2f * z1;
            float p0 = red16(m0 * att0);
            float p1 = red16(m1 * att1);
            float ex0 = __expf(p0), ex1 = __expf(p1);
            den0 += ex0; den1 += ex1;
            acc0 = fmaf(ex0, xc.x, acc0);
            acc1 = fmaf(ex1, xc.y, acc1);
        };

        int2 seA, seB; EwReg<T> wA, wB; float2 xA, xB;
        if (cnt > 0) {
            seA = csr[beg]; wA.load(ew, seA.y);
            xA = *(const float2*)(xl + (size_t)seA.x * D + 2 * l);
        }
        if (cnt > 1) {
            seB = csr[beg + 1]; wB.load(ew, seB.y);
            xB = *(const float2*)(xl + (size_t)seB.x * D + 2 * l);
        }
        for (int j = beg; j + 1 < end; j += 2) {
            EwReg<T> cwA = wA, cwB = wB;
            float2 cxA = xA, cxB = xB;
            int rem = end - (j + 2);
            if (rem > 0) {
                seA = csr[j + 2]; wA.load(ew, seA.y);
                xA = *(const float2*)(xl + (size_t)seA.x * D + 2 * l);
            }
            if (rem > 1) {
                seB = csr[j + 3]; wB.load(ew, seB.y);
                xB = *(const float2*)(xl + (size_t)seB.x * D + 2 * l);
            }
            edge_eval(cwA, cxA);
            edge_eval(cwB, cxB);
        }
        if (cnt & 1) edge_eval(wA, xA);

        float v0 = (den0 > 0.f ? acc0 / den0 : 0.f) + b0;
        float v1 = (den1 > 0.f ? acc1 / den1 : 0.f) + b1;
        float* vp = vpre + (size_t)i * D + 2 * l;
        vp[0] = v0; vp[1] = v1;
        s0 += v0; s20 += v0 * v0;
        s1 += v1; s21 += v1 * v1;
    }

    __shared__ float sh[4][2][64], sh2[4][2][64];
    sh[slot][0][l] = s0;  sh[slot][1][l] = s1;
    sh2[slot][0][l] = s20; sh2[slot][1][l] = s21;
    __syncthreads();
    if (t < 128) {
        int s_ = t >> 6, l2 = t & 63;
        int d = l2 + 64 * s_;
        float a = 0, a2 = 0;
        #pragma unroll
        for (int q = 0; q < 4; ++q) { a += sh[q][s_][l2]; a2 += sh2[q][s_][l2]; }
        atomicAdd(&bnsum[d], a);
        atomicAdd(&bnsumsq[d], a2);
    }
}

__global__ __launch_bounds__(256) void k_agg_bf16(
    const int* row_ptr, const int2* csr, const void* ew, const void* We,
    const void* att, const void* bias, const float* xl, const float* xr,
    float* vpre, float* bnsum, float* bnsumsq, int n, const int* flag)
{
    if (*flag) return;
    agg_body<bf16>(row_ptr, csr, (const bf16*)ew, (const bf16*)We,
                   (const bf16*)att, (const bf16*)bias, xl, xr,
                   vpre, bnsum, bnsumsq, n);
}

__global__ __launch_bounds__(256) void k_agg_f32(
    const int* row_ptr, const int2* csr, const void* ew, const void* We,
    const void* att, const void* bias, const float* xl, const float* xr,
    float* vpre, float* bnsum, float* bnsumsq, int n, const int* flag)
{
    if (*flag == 0) return;
    agg_body<float>(row_ptr, csr, (const float*)ew, (const float*)We,
                    (const float*)att, (const float*)bias, xl, xr,
                    vpre, bnsum, bnsumsq, n);
}

// ------------------------------------------------------------- finalize
template <typename T>
__device__ __forceinline__ void final_body(
    const float* __restrict__ vpre, const T* __restrict__ gamma,
    const T* __restrict__ beta, const float* __restrict__ bnsum,
    const float* __restrict__ bnsumsq, float* __restrict__ out, int n)
{
    int idx = blockIdx.x * blockDim.x + threadIdx.x;
    if (idx >= n * D) return;
    int p = idx & (D - 1);
    int d = (p >> 1) + ((p & 1) << 6);   // undo interleave
    float v = vpre[idx];
    float invN = 1.0f / (float)n;
    float mean = bnsum[d] * invN;
    float var = bnsumsq[d] * invN - mean * mean;
    float y = (v - mean) * rsqrtf(var + 1e-5f) * cvt(gamma[d]) + cvt(beta[d]);
    y = y > 0.0f ? y : 0.01f * y;        // leaky_relu 0.01
    int row = idx >> 7;
    out[(size_t)row * D + d] = y;        // fp32 output, natural layout
}

__global__ __launch_bounds__(256) void k_final(
    const float* vpre, const void* gamma, const void* beta,
    const float* bnsum, const float* bnsumsq, float* out, int n,
    const int* flag)
{
    if (*flag)
        final_body<float>(vpre, (const float*)gamma, (const float*)beta,
                          bnsum, bnsumsq, out, n);
    else
        final_body<bf16>(vpre, (const bf16*)gamma, (const bf16*)beta,
                         bnsum, bnsumsq, out, n);
}

// ---------------------------------------------------------------- launch
extern "C" void kernel_launch(void* const* d_in, const int* in_sizes, int n_in,
                              void* d_out, int out_size, void* d_ws, size_t ws_size,
                              hipStream_t stream)
{
    const int*  x     = (const int*)d_in[0];
    const int*  ei    = (const int*)d_in[1];
    const void* ew    = d_in[2];
    const void* emb   = d_in[3];
    const void* Wl    = d_in[4];
    const void* bl    = d_in[5];
    const void* Wr    = d_in[6];
    const void* br    = d_in[7];
    const void* att   = d_in[8];
    const void* We    = d_in[9];
    const void* bias  = d_in[10];
    const void* gamma = d_in[11];
    const void* beta  = d_in[12];

    const int n  = in_sizes[0];        // 50000
    const int nE = in_sizes[1] / 2;    // 800000

    // ws layout: xl | xr | vpre | deg | bnsum | bnsumsq | flag | row_ptr | cursor | csr
    float* ws      = (float*)d_ws;
    float* xl      = ws;
    float* xr      = xl + (size_t)n * D;
    float* vpre    = xr + (size_t)n * D;
    int*   deg     = (int*)(vpre + (size_t)n * D);
    float* bnsum   = (float*)(deg + n);
    float* bnsumsq = bnsum + D;
    int*   flag    = (int*)(bnsumsq + D);
    int*   row_ptr = flag + 1;
    int*   cursor  = row_ptr + (n + 1);
    uintptr_t p    = (uintptr_t)(cursor + n);
    p = (p + 7) & ~(uintptr_t)7;
    int2*  csr     = (int2*)p;

    int zcount = n + 2 * D;            // deg + bnsum + bnsumsq
    k_zero_detect<<<(zcount + 255) / 256, 256, 0, stream>>>(
        deg, zcount, (const u16*)emb, flag);

    int nodeBlocks = (n + MT - 1) / MT;
    int histBlocks = (nE + 255) / 256;
    k_node_mfma<<<nodeBlocks + histBlocks, 256, 0, stream>>>(
        x, emb, Wl, bl, Wr, br, xl, xr, n, flag, ei, deg, nE, nodeBlocks);
    k_node_f32<<<nodeBlocks, 256, 0, stream>>>(
        x, (const float*)emb, (const float*)Wl, (const float*)bl,
        (const float*)Wr, (const float*)br, xl, xr, n, flag);

    k_scan<<<1, 1024, 0, stream>>>(deg, row_ptr, cursor, n);

    k_scatter<<<(nE + 255) / 256, 256, 0, stream>>>(ei, cursor, csr, nE);

    k_agg_bf16<<<2500, 256, 0, stream>>>(row_ptr, csr, ew, We, att, bias,
                                         xl, xr, vpre, bnsum, bnsumsq, n, flag);
    k_agg_f32<<<2500, 256, 0, stream>>>(row_ptr, csr, ew, We, att, bias,
                                        xl, xr, vpre, bnsum, bnsumsq, n, flag);

    int totalOut = n * D;
    k_final<<<(totalOut + 255) / 256, 256, 0, stream>>>(vpre, gamma, beta,
                                                        bnsum, bnsumsq,
                                                        (float*)d_out, n, flag);
}

// Round 6
// 574.600 us; speedup vs baseline: 1.2241x; 1.2241x over previous
//
#include <hip/hip_runtime.h>
#include <hip/hip_bf16.h>

typedef __hip_bfloat16 bf16;
typedef unsigned short u16;

#define D 128
#define EDIM 16
#define SQRT_D 11.313708498984761f

typedef short bf16x8 __attribute__((ext_vector_type(8)));
typedef float f32x4 __attribute__((ext_vector_type(4)));

// pf (prepped fp32 params) layout, in floats
#define PF_BL    0
#define PF_BR    128
#define PF_WE    256
#define PF_ATT   2304
#define PF_BIAS  2432
#define PF_GAMMA 2560
#define PF_BETA  2688
#define PF_TOTAL 2816

__device__ __forceinline__ u16 f2bf_bits(float f) {
    union { bf16 h; u16 s; } cv; cv.h = __float2bfloat16(f); return cv.s;
}
// XOR-swizzled index for W^T bf16 tiles: row nn (output channel), col k.
// 8-element blocks permuted by nn&15 -> conflict-free ds_read_b128.
__device__ __forceinline__ int swid(int nn, int k) {
    return nn * 128 + ((((k >> 3) ^ (nn & 15)) << 3) | (k & 7));
}
// 8-lane all-reduce sum via DPP (xor1, xor2, half-mirror) — stays in 8-group
__device__ __forceinline__ float red8(float x) {
    x += __int_as_float(__builtin_amdgcn_update_dpp(0, __float_as_int(x), 0xB1, 0xf, 0xf, true));
    x += __int_as_float(__builtin_amdgcn_update_dpp(0, __float_as_int(x), 0x4E, 0xf, 0xf, true));
    x += __int_as_float(__builtin_amdgcn_update_dpp(0, __float_as_int(x), 0x141, 0xf, 0xf, true));
    return x;
}

// --------------------------------------- zero fill + dtype detect (block 0)
__global__ void k_zero_detect(int* p, int count, const u16* __restrict__ u, int* flag)
{
    int i = blockIdx.x * blockDim.x + threadIdx.x;
    if (i < count) p[i] = 0;
    if (blockIdx.x == 0) {
        __shared__ int sh[256];
        int t = threadIdx.x;
        int cnt = 0;
        for (int k = t; k < 4096; k += 256) {
            int e = (u[k] >> 7) & 0xFF;
            cnt += (e > 132 && e < 255) ? 1 : 0;
        }
        sh[t] = cnt;
        __syncthreads();
        for (int s = 128; s > 0; s >>= 1) {
            if (t < s) sh[t] += sh[t + s];
            __syncthreads();
        }
        if (t == 0) *flag = (sh[0] > 100) ? 1 : 0;
    }
}

__device__ __forceinline__ float rdv(const void* p, int i, int fl) {
    return fl ? ((const float*)p)[i] : __bfloat162float(((const bf16*)p)[i]);
}

// ---------------- prep (emb->bf16, W^T->bf16 swizzled, params->f32) + hist
__global__ __launch_bounds__(256) void k_prep_hist(
    const void* emb, const void* Wl, const void* Wr,
    const void* bl, const void* br, const void* We, const void* att,
    const void* bias, const void* gamma, const void* beta,
    const int* __restrict__ flag, u16* __restrict__ emb16,
    u16* __restrict__ WT, float* __restrict__ pf,
    const int* __restrict__ ei, int* __restrict__ deg,
    int nE, int embCount, int prepBlocks)
{
    if ((int)blockIdx.x >= prepBlocks) {              // fused dst histogram
        int e = (blockIdx.x - prepBlocks) * 256 + threadIdx.x;
        if (e < nE) atomicAdd(&deg[ei[nE + e]], 1);
        return;
    }
    const int fl = *flag;
    int idx = blockIdx.x * 256 + threadIdx.x;
    if (idx < embCount) {
        emb16[idx] = f2bf_bits(rdv(emb, idx, fl) * SQRT_D);
        return;
    }
    idx -= embCount;
    if (idx < 32768) {            // W transpose: w=idx>>14, j=idx&16383
        int w = idx >> 14;
        int j = idx & 16383;
        int k = j >> 7, nn = j & 127;
        const void* W = w ? Wr : Wl;
        WT[w * 16384 + swid(nn, k)] = f2bf_bits(rdv(W, k * D + nn, fl));
        return;
    }
    idx -= 32768;
    if (idx < 128)  { pf[PF_BL + idx] = rdv(bl, idx, fl); return; }
    idx -= 128;
    if (idx < 128)  { pf[PF_BR + idx] = rdv(br, idx, fl); return; }
    idx -= 128;
    if (idx < 2048) { pf[PF_WE + idx] = rdv(We, idx, fl); return; }
    idx -= 2048;
    if (idx < 128)  { pf[PF_ATT + idx] = rdv(att, idx, fl); return; }
    idx -= 128;
    if (idx < 128)  { pf[PF_BIAS + idx] = rdv(bias, idx, fl); return; }
    idx -= 128;
    if (idx < 128)  { pf[PF_GAMMA + idx] = rdv(gamma, idx, fl); return; }
    idx -= 128;
    if (idx < 128)  { pf[PF_BETA + idx] = rdv(beta, idx, fl); return; }
}

// ---------------------------------------------- CSR scan (single block)
__global__ __launch_bounds__(1024) void k_scan(
    const int* __restrict__ deg, int* __restrict__ row_ptr,
    int* __restrict__ cursor, int n)
{
    __shared__ int part[1024];
    const int t = threadIdx.x;
    const int chunk = (n + 1023) >> 10;
    const int beg = t * chunk;
    const int end = min(beg + chunk, n);
    int s = 0;
    for (int i = beg; i < end; ++i) s += deg[i];
    part[t] = s;
    __syncthreads();
    for (int off = 1; off < 1024; off <<= 1) {
        int v = (t >= off) ? part[t - off] : 0;
        __syncthreads();
        part[t] += v;
        __syncthreads();
    }
    int run = (t > 0) ? part[t - 1] : 0;
    for (int i = beg; i < end; ++i) {
        row_ptr[i] = run;
        cursor[i] = run;
        run += deg[i];
    }
    if (t == 1023) row_ptr[n] = part[1023];
}

// --------------------------- CSR scatter: store (src byte-offset, edge id)
__global__ void k_scatter(const int* __restrict__ ei, int* __restrict__ cursor,
                          int2* __restrict__ csr, int nE)
{
    int e = blockIdx.x * blockDim.x + threadIdx.x;
    if (e < nE) {
        int src = ei[e], dst = ei[nE + e];
        int pos = atomicAdd(&cursor[dst], 1);
        csr[pos] = make_int2(src << 9, e);   // src*512 = xl row byte offset
    }
}

// ------------------- node transform via MFMA 16x16x32_bf16, 64-row tiles
// A-frags gathered directly from global emb16 (per-lane token rows);
// both W^T tiles staged once in LDS (swizzled), reused for xl and xr pass.
__global__ __launch_bounds__(256) void k_node(
    const int* __restrict__ x, const u16* __restrict__ emb16,
    const u16* __restrict__ WT, const float* __restrict__ pf,
    float* __restrict__ xl, float* __restrict__ xr, int n)
{
    __shared__ u16 Bt[2][16384];
    const int t = threadIdx.x;
    {   // linear 64 KB copy, conflict-free
        const uint4* s = (const uint4*)WT;
        uint4* dd = (uint4*)&Bt[0][0];
        #pragma unroll
        for (int i = 0; i < 16; ++i) dd[i * 256 + t] = s[i * 256 + t];
    }
    const int l = t & 63;
    const int wv = t >> 6;
    const int m = l & 15;
    const int quad = l >> 4;
    const int R = blockIdx.x * 64;

    int arow = R + wv * 16 + m;
    int tok = (arow < n) ? x[arow] : 0;
    const u16* ap = emb16 + (size_t)tok * D + quad * 8;
    bf16x8 afr[4];
    #pragma unroll
    for (int kk = 0; kk < 4; ++kk) afr[kk] = *(const bf16x8*)(ap + kk * 32);
    __syncthreads();

    #pragma unroll
    for (int w = 0; w < 2; ++w) {
        const float* bb = pf + (w ? PF_BR : PF_BL);
        float* out = w ? xr : xl;
        f32x4 acc[8];
        #pragma unroll
        for (int nt = 0; nt < 8; ++nt) {
            float bv = bb[nt * 16 + m];
            acc[nt] = f32x4{bv, bv, bv, bv};
        }
        #pragma unroll
        for (int kk = 0; kk < 4; ++kk) {
            #pragma unroll
            for (int nt = 0; nt < 8; ++nt) {
                int blk = (quad + 4 * kk) ^ m;
                bf16x8 bfr = *(const bf16x8*)&Bt[w][(nt * 16 + m) * 128 + blk * 8];
                acc[nt] = __builtin_amdgcn_mfma_f32_16x16x32_bf16(afr[kk], bfr, acc[nt], 0, 0, 0);
            }
        }
        #pragma unroll
        for (int nt = 0; nt < 8; ++nt) {
            int col = nt * 16 + m;
            #pragma unroll
            for (int r = 0; r < 4; ++r) {
                int row = R + wv * 16 + quad * 4 + r;
                if (row < n) out[(size_t)row * D + col] = acc[nt][r];
            }
        }
    }
}

// ------------------------------------------------ per-edge ew row registers
template <typename T> struct EwReg;
template <> struct EwReg<bf16> {
    unsigned v[8];
    __device__ __forceinline__ void load(const char* base, int e) {
        const uint4* q = (const uint4*)(base + ((size_t)e << 5));
        uint4 A = q[0], B = q[1];
        v[0]=A.x; v[1]=A.y; v[2]=A.z; v[3]=A.w;
        v[4]=B.x; v[5]=B.y; v[6]=B.z; v[7]=B.w;
    }
    __device__ __forceinline__ float2 pair(int q) const {
        return make_float2(__uint_as_float(v[q] << 16),
                           __uint_as_float(v[q] & 0xffff0000u));
    }
};
template <> struct EwReg<float> {
    float v[16];
    __device__ __forceinline__ void load(const char* base, int e) {
        const float4* q = (const float4*)(base + ((size_t)e << 6));
        float4 A = q[0], B = q[1], Cc = q[2], Dd = q[3];
        v[0]=A.x; v[1]=A.y; v[2]=A.z; v[3]=A.w;
        v[4]=B.x; v[5]=B.y; v[6]=B.z; v[7]=B.w;
        v[8]=Cc.x; v[9]=Cc.y; v[10]=Cc.z; v[11]=Cc.w;
        v[12]=Dd.x; v[13]=Dd.y; v[14]=Dd.z; v[15]=Dd.w;
    }
    __device__ __forceinline__ float2 pair(int q) const {
        return make_float2(v[2 * q], v[2 * q + 1]);
    }
};

// ---------------- node-centric aggregation: 1 wave = 1 node, 4 nodes/wave
// lane l owns channels 2l, 2l+1 (same head l>>3): 3-DPP reduce, 1 expf/edge.
template <typename T>
__device__ __forceinline__ void agg_body(
    const int* __restrict__ row_ptr, const int2* __restrict__ csr,
    const T* __restrict__ ew, const float* __restrict__ pf,
    const float* __restrict__ xl, const float* __restrict__ xr,
    float* __restrict__ vpre, float* __restrict__ bnsum,
    float* __restrict__ bnsumsq, int n)
{
    const int t = threadIdx.x;
    const int l = t & 63;
    const int wv = t >> 6;

    float2 we[EDIM];
    #pragma unroll
    for (int k = 0; k < EDIM; ++k)
        we[k] = *(const float2*)&pf[PF_WE + k * D + 2 * l];
    const float2 attv  = *(const float2*)&pf[PF_ATT + 2 * l];
    const float2 biasv = *(const float2*)&pf[PF_BIAS + 2 * l];

    const char* xlB = (const char*)xl + 8 * l;
    const char* ewB = (const char*)ew;

    float s0 = 0, s20 = 0, s1 = 0, s21 = 0;
    const int slot = blockIdx.x * 4 + wv;
    const int i0 = slot * 4;
    const int i1 = min(i0 + 4, n);

    for (int i = i0; i < i1; ++i) {
        const int beg = row_ptr[i], end = row_ptr[i + 1];
        const int cnt = end - beg;
        const float2 xrv = *(const float2*)(xr + (size_t)i * D + 2 * l);
        float acc0 = 0, acc1 = 0, den = 0;

        EwReg<T> wA, wB;
        float2 xA, xB;

        auto comp = [&](const EwReg<T>& w, float2 xc) {
            float e0 = xrv.x, e1 = xrv.y;
            #pragma unroll
            for (int q = 0; q < 8; ++q) {
                float2 pr = w.pair(q);
                e0 = fmaf(pr.x, we[2*q].x,   e0);
                e0 = fmaf(pr.y, we[2*q+1].x, e0);
                e1 = fmaf(pr.x, we[2*q].y,   e1);
                e1 = fmaf(pr.y, we[2*q+1].y, e1);
            }
            float z0 = xc.x + e0, z1 = xc.y + e1;
            float m0 = fmaxf(z0, 0.2f * z0);      // leaky_relu 0.2
            float m1 = fmaxf(z1, 0.2f * z1);
            float p = red8(fmaf(m1, attv.y, m0 * attv.x));
            float ex = __expf(p);
            den += ex;
            acc0 = fmaf(ex, xc.x, acc0);
            acc1 = fmaf(ex, xc.y, acc1);
        };

        if (cnt > 0) { int2 c = csr[beg];     wA.load(ewB, c.y); xA = *(const float2*)(xlB + c.x); }
        if (cnt > 1) { int2 c = csr[beg + 1]; wB.load(ewB, c.y); xB = *(const float2*)(xlB + c.x); }

        for (int j = beg; j + 1 < end; j += 2) {
            comp(wA, xA);
            if (j + 2 < end) { int2 c = csr[j + 2]; wA.load(ewB, c.y); xA = *(const float2*)(xlB + c.x); }
            comp(wB, xB);
            if (j + 3 < end) { int2 c = csr[j + 3]; wB.load(ewB, c.y); xB = *(const float2*)(xlB + c.x); }
        }
        if (cnt & 1) comp(wA, xA);

        float inv = den > 0.f ? 1.0f / den : 0.0f;
        float v0 = acc0 * inv + biasv.x;
        float v1 = acc1 * inv + biasv.y;
        float2* vp = (float2*)(vpre + (size_t)i * D + 2 * l);
        *vp = make_float2(v0, v1);
        s0 += v0; s20 += v0 * v0;
        s1 += v1; s21 += v1 * v1;
    }

    __shared__ float sh[4][D], sh2[4][D];
    sh[wv][2*l] = s0;   sh[wv][2*l+1] = s1;
    sh2[wv][2*l] = s20; sh2[wv][2*l+1] = s21;
    __syncthreads();
    if (t < D) {
        float a = 0, a2 = 0;
        #pragma unroll
        for (int q = 0; q < 4; ++q) { a += sh[q][t]; a2 += sh2[q][t]; }
        atomicAdd(&bnsum[t], a);
        atomicAdd(&bnsumsq[t], a2);
    }
}

__global__ __launch_bounds__(256) void k_agg(
    const int* row_ptr, const int2* csr, const void* ew, const float* pf,
    const float* xl, const float* xr, float* vpre, float* bnsum,
    float* bnsumsq, int n, const int* flag)
{
    if (*flag)
        agg_body<float>(row_ptr, csr, (const float*)ew, pf, xl, xr,
                        vpre, bnsum, bnsumsq, n);
    else
        agg_body<bf16>(row_ptr, csr, (const bf16*)ew, pf, xl, xr,
                       vpre, bnsum, bnsumsq, n);
}

// ------------------------------------------------------------- finalize
__global__ __launch_bounds__(256) void k_final(
    const float* __restrict__ vpre, const float* __restrict__ pf,
    const float* __restrict__ bnsum, const float* __restrict__ bnsumsq,
    float* __restrict__ out, int n)
{
    int idx = blockIdx.x * 256 + threadIdx.x;
    if (idx >= n * (D / 4)) return;
    int pos = idx * 4;
    int d = pos & (D - 1);
    const float invN = 1.0f / (float)n;
    float4 v  = *(const float4*)(vpre + pos);
    float4 ms = *(const float4*)(bnsum + d);
    float4 m2 = *(const float4*)(bnsumsq + d);
    float4 g  = *(const float4*)(pf + PF_GAMMA + d);
    float4 bt = *(const float4*)(pf + PF_BETA + d);
    float* vv = (float*)&v; float* msv = (float*)&ms; float* m2v = (float*)&m2;
    float* gv = (float*)&g; float* btv = (float*)&bt;
    float4 o;
    float* ov = (float*)&o;
    #pragma unroll
    for (int c = 0; c < 4; ++c) {
        float mean = msv[c] * invN;
        float var = m2v[c] * invN - mean * mean;
        float y = (vv[c] - mean) * rsqrtf(var + 1e-5f) * gv[c] + btv[c];
        ov[c] = y > 0.f ? y : 0.01f * y;          // leaky_relu 0.01
    }
    *(float4*)(out + pos) = o;
}

// ---------------------------------------------------------------- launch
extern "C" void kernel_launch(void* const* d_in, const int* in_sizes, int n_in,
                              void* d_out, int out_size, void* d_ws, size_t ws_size,
                              hipStream_t stream)
{
    const int*  x     = (const int*)d_in[0];
    const int*  ei    = (const int*)d_in[1];
    const void* ew    = d_in[2];
    const void* emb   = d_in[3];
    const void* Wl    = d_in[4];
    const void* bl    = d_in[5];
    const void* Wr    = d_in[6];
    const void* br    = d_in[7];
    const void* att   = d_in[8];
    const void* We    = d_in[9];
    const void* bias  = d_in[10];
    const void* gamma = d_in[11];
    const void* beta  = d_in[12];

    const int n  = in_sizes[0];
    const int nE = in_sizes[1] / 2;
    const int embCount = in_sizes[3];

    float* ws      = (float*)d_ws;
    float* xl      = ws;
    float* xr      = xl + (size_t)n * D;
    float* vpre    = xr + (size_t)n * D;
    int*   deg     = (int*)(vpre + (size_t)n * D);
    float* bnsum   = (float*)(deg + n);
    float* bnsumsq = bnsum + D;
    int*   flag    = (int*)(bnsumsq + D);
    int*   row_ptr = flag + 1;
    int*   cursor  = row_ptr + (n + 1);
    uintptr_t p    = (uintptr_t)(cursor + n);
    p = (p + 15) & ~(uintptr_t)15;
    int2*  csr     = (int2*)p;
    p = (uintptr_t)(csr + nE);
    p = (p + 15) & ~(uintptr_t)15;
    u16*   emb16   = (u16*)p;
    p = (uintptr_t)(emb16 + embCount);
    p = (p + 15) & ~(uintptr_t)15;
    u16*   WT      = (u16*)p;
    p = (uintptr_t)(WT + 32768);
    float* pf      = (float*)p;

    int zc = n + 2 * D;
    k_zero_detect<<<(zc + 255) / 256, 256, 0, stream>>>(deg, zc, (const u16*)emb, flag);

    int prepN = embCount + 32768 + PF_TOTAL;
    int prepBlocks = (prepN + 255) / 256;
    int histBlocks = (nE + 255) / 256;
    k_prep_hist<<<prepBlocks + histBlocks, 256, 0, stream>>>(
        emb, Wl, Wr, bl, br, We, att, bias, gamma, beta,
        flag, emb16, WT, pf, ei, deg, nE, embCount, prepBlocks);

    k_scan<<<1, 1024, 0, stream>>>(deg, row_ptr, cursor, n);

    k_scatter<<<histBlocks, 256, 0, stream>>>(ei, cursor, csr, nE);

    k_node<<<(n + 63) / 64, 256, 0, stream>>>(x, emb16, WT, pf, xl, xr, n);

    int aggBlocks = (n + 15) / 16;   // 4 waves x 4 nodes per block
    k_agg<<<aggBlocks, 256, 0, stream>>>(row_ptr, csr, ew, pf, xl, xr,
                                         vpre, bnsum, bnsumsq, n, flag);

    k_final<<<(n * (D / 4) + 255) / 256, 256, 0, stream>>>(
        vpre, pf, bnsum, bnsumsq, (float*)d_out, n);
}